// Round 1
// baseline (368.209 us; speedup 1.0000x reference)
//
#include <hip/hip_runtime.h>
#include <hip/hip_bf16.h>
#include <math.h>

#define C_DIM 1024
#define CR    256
#define A_N   10
#define NANCH 3
#define B_N   2
#define HW_N  4096
#define NTOK  (B_N*HW_N)   // 8192
#define KG2   (A_N*CR)     // 2560

typedef unsigned short ushort_t;
typedef __attribute__((ext_vector_type(4))) float f32x4;
typedef __attribute__((ext_vector_type(8))) short bf16x8;

__device__ __forceinline__ ushort_t f2bf(float x) {
    __hip_bfloat16 h = __float2bfloat16(x);
    return *reinterpret_cast<ushort_t*>(&h);
}

// ---------------- weight prep ----------------
// w1t[a][d][c] = bf16(ln_scale[a][c] * w1[a][c][d])   (N-major for NT gemm)
__global__ __launch_bounds__(256) void prep_w1t(const float* __restrict__ w1,
                                                const float* __restrict__ ln_s,
                                                ushort_t* __restrict__ w1t) {
    int d0 = blockIdx.x * 64, c0 = blockIdx.y * 64, a = blockIdx.z;
    __shared__ float lds[64][65];
    int tid = threadIdx.x, lo = tid & 63, hi = tid >> 6;
    #pragma unroll
    for (int i = 0; i < 16; i++) {
        int c_l = i * 4 + hi;
        lds[c_l][lo] = w1[((size_t)a * C_DIM + c0 + c_l) * CR + d0 + lo] * ln_s[a * C_DIM + c0 + c_l];
    }
    __syncthreads();
    #pragma unroll
    for (int i = 0; i < 16; i++) {
        int d_l = i * 4 + hi;
        w1t[((size_t)a * CR + d0 + d_l) * C_DIM + c0 + lo] = f2bf(lds[lo][d_l]);
    }
}

// w2t[c][a*CR+d] = bf16(w2[a][d][c])  i.e. transpose of flat [2560][1024]
__global__ __launch_bounds__(256) void prep_w2t(const float* __restrict__ w2,
                                                ushort_t* __restrict__ w2t) {
    int k0 = blockIdx.x * 64, c0 = blockIdx.y * 64;
    __shared__ float lds[64][65];
    int tid = threadIdx.x, lo = tid & 63, hi = tid >> 6;
    #pragma unroll
    for (int i = 0; i < 16; i++) {
        int k_l = i * 4 + hi;
        lds[k_l][lo] = w2[((size_t)k0 + k_l) * C_DIM + c0 + lo];
    }
    __syncthreads();
    #pragma unroll
    for (int i = 0; i < 16; i++) {
        int c_l = i * 4 + hi;
        w2t[((size_t)c0 + c_l) * KG2 + k0 + lo] = f2bf(lds[lo][c_l]);
    }
}

// bias1[a][d] = sum_c ln_bias[a][c] * w1[a][c][d]
__global__ __launch_bounds__(256) void bias1k(const float* __restrict__ w1,
                                              const float* __restrict__ ln_b,
                                              float* __restrict__ bias1) {
    int c0 = blockIdx.x * 64, a = blockIdx.y, d = threadIdx.x;
    float s = 0.f;
    for (int c = c0; c < c0 + 64; c++)
        s += ln_b[a * C_DIM + c] * w1[((size_t)a * C_DIM + c) * CR + d];
    atomicAdd(&bias1[a * CR + d], s);
}

// ---------------- LN ----------------
__global__ __launch_bounds__(256) void ln_stats(const float* __restrict__ feat,
                                                float* __restrict__ meanp,
                                                float* __restrict__ rstdp) {
    int blk = blockIdx.x;            // 128 blocks: 64 pixels each
    int b = blk >> 6;
    int p0 = (blk & 63) * 64;
    int tid = threadIdx.x, p = tid & 63, cs = tid >> 6;
    float s = 0.f, s2 = 0.f;
    for (int c = cs; c < C_DIM; c += 4) {
        float v = feat[((size_t)b * C_DIM + c) * HW_N + p0 + p];
        s += v; s2 += v * v;
    }
    __shared__ float sh[8][64];
    sh[cs][p] = s; sh[cs + 4][p] = s2;
    __syncthreads();
    if (tid < 64) {
        float ss = sh[0][tid] + sh[1][tid] + sh[2][tid] + sh[3][tid];
        float qq = sh[4][tid] + sh[5][tid] + sh[6][tid] + sh[7][tid];
        float mean = ss * (1.f / C_DIM);
        float var = qq * (1.f / C_DIM) - mean * mean;
        meanp[b * HW_N + p0 + tid] = mean;
        rstdp[b * HW_N + p0 + tid] = rsqrtf(var + 1e-5f);
    }
}

// normG[t][c] = bf16((feat - mean)*rstd), token-major
__global__ __launch_bounds__(256) void normk(const float* __restrict__ feat,
                                             const float* __restrict__ meanp,
                                             const float* __restrict__ rstdp,
                                             ushort_t* __restrict__ normG) {
    int p0 = blockIdx.x * 64, c0 = blockIdx.y * 64, b = blockIdx.z;
    __shared__ float lds[64][65];
    int tid = threadIdx.x, lo = tid & 63, hi = tid >> 6;
    #pragma unroll
    for (int i = 0; i < 16; i++) {
        int c_l = i * 4 + hi;
        lds[c_l][lo] = feat[((size_t)b * C_DIM + c0 + c_l) * HW_N + p0 + lo];
    }
    __syncthreads();
    #pragma unroll
    for (int i = 0; i < 16; i++) {
        int p_l = i * 4 + hi;
        int t = b * HW_N + p0 + p_l;
        float m = meanp[t], r = rstdp[t];
        normG[(size_t)t * C_DIM + c0 + lo] = f2bf((lds[lo][p_l] - m) * r);
    }
}

// ---------------- selection weights ----------------
__global__ __launch_bounds__(256) void wselk(const float* __restrict__ ar,
                                             float* __restrict__ wsel) {
    int t = blockIdx.x * 256 + threadIdx.x;  // < 8192
    int b = t >> 12, p = t & (HW_N - 1);
    const float THR[9] = {1.0f/9.0f, 1.0f/7.0f, 0.2f, 1.0f/3.0f, 1.0f, 3.0f, 5.0f, 7.0f, 9.0f};
    int cnt[A_N];
    #pragma unroll
    for (int a = 0; a < A_N; a++) cnt[a] = 0;
    #pragma unroll
    for (int na = 0; na < NANCH; na++) {
        float v = ar[(size_t)b * NANCH * HW_N + na * HW_N + p];
        int idx = 0;
        #pragma unroll
        for (int i = 0; i < 9; i++) idx += (v > THR[i]) ? 1 : 0;
        #pragma unroll
        for (int a = 0; a < A_N; a++) cnt[a] += (idx == a) ? 1 : 0;
    }
    #pragma unroll
    for (int a = 0; a < A_N; a++) wsel[a * NTOK + t] = cnt[a] * (1.0f / 3.0f);
}

// ---------------- 128x128 bf16 MFMA GEMM core (NT: A[M][K], B[N][K]) ----------------
__device__ __forceinline__ void gemm_core_128x128(
    const ushort_t* __restrict__ Ag, int lda,
    const ushort_t* __restrict__ Bg, int ldb,
    int K, ushort_t* As, ushort_t* Bs, f32x4 acc[4][4]) {
    const int tid = threadIdx.x;
    const int lane = tid & 63;
    const int w = tid >> 6;
    const int wr = w >> 1, wc = w & 1;
    const int lrow = lane & 15;
    const int quad = lane >> 4;

    #pragma unroll
    for (int i = 0; i < 4; i++)
        #pragma unroll
        for (int j = 0; j < 4; j++)
            #pragma unroll
            for (int e = 0; e < 4; e++) acc[i][j][e] = 0.f;

    const int srow = w * 32 + (lane >> 3);   // staging row (+i*8)
    const int scol = (lane & 7) * 8;         // staging col (8 bf16 = 16B)

    for (int k0 = 0; k0 < K; k0 += 64) {
        __syncthreads();
        #pragma unroll
        for (int i = 0; i < 4; i++) {
            const ushort_t* gA = Ag + (size_t)(srow + i * 8) * lda + k0 + scol;
            __builtin_amdgcn_global_load_lds(
                (__attribute__((address_space(1))) void*)gA,
                (__attribute__((address_space(3))) void*)(As + (w * 32 + i * 8) * 64),
                16, 0, 0);
            const ushort_t* gB = Bg + (size_t)(srow + i * 8) * ldb + k0 + scol;
            __builtin_amdgcn_global_load_lds(
                (__attribute__((address_space(1))) void*)gB,
                (__attribute__((address_space(3))) void*)(Bs + (w * 32 + i * 8) * 64),
                16, 0, 0);
        }
        __syncthreads();
        #pragma unroll
        for (int ks = 0; ks < 2; ks++) {
            bf16x8 af[4], bfr[4];
            #pragma unroll
            for (int mt = 0; mt < 4; mt++)
                af[mt] = *(const bf16x8*)(As + (wr * 64 + mt * 16 + lrow) * 64 + ks * 32 + quad * 8);
            #pragma unroll
            for (int nt = 0; nt < 4; nt++)
                bfr[nt] = *(const bf16x8*)(Bs + (wc * 64 + nt * 16 + lrow) * 64 + ks * 32 + quad * 8);
            #pragma unroll
            for (int mt = 0; mt < 4; mt++)
                #pragma unroll
                for (int nt = 0; nt < 4; nt++)
                    acc[mt][nt] = __builtin_amdgcn_mfma_f32_16x16x32_bf16(af[mt], bfr[nt], acc[mt][nt], 0, 0, 0);
        }
    }
}

// GEMM1: H = gelu(norm @ w1'[a] + bias1[a]) * wsel[a]  -> G[t][a*256+d] bf16
__global__ __launch_bounds__(256) void gemm1(const ushort_t* __restrict__ normG,
                                             const ushort_t* __restrict__ w1t,
                                             const float* __restrict__ bias1,
                                             const float* __restrict__ wsel,
                                             ushort_t* __restrict__ G) {
    __shared__ __align__(16) ushort_t As[128 * 64];
    __shared__ __align__(16) ushort_t Bs[128 * 64];
    int n0 = blockIdx.x * 128;
    int m0 = blockIdx.y * 128;
    int a = blockIdx.z;
    f32x4 acc[4][4];
    gemm_core_128x128(normG + (size_t)m0 * C_DIM, C_DIM,
                      w1t + ((size_t)a * CR + n0) * C_DIM, C_DIM,
                      C_DIM, As, Bs, acc);
    int tid = threadIdx.x, lane = tid & 63, w = tid >> 6;
    int wr = w >> 1, wc = w & 1, lrow = lane & 15, quad = lane >> 4;
    #pragma unroll
    for (int mt = 0; mt < 4; mt++)
        #pragma unroll
        for (int r = 0; r < 4; r++) {
            int row = m0 + wr * 64 + mt * 16 + quad * 4 + r;
            float wv = wsel[a * NTOK + row];
            #pragma unroll
            for (int nt = 0; nt < 4; nt++) {
                int col = n0 + wc * 64 + nt * 16 + lrow;
                float v = acc[mt][nt][r] + bias1[a * CR + col];
                float g = 0.5f * v * (1.0f + erff(v * 0.70710678118654752f));
                G[(size_t)row * KG2 + a * CR + col] = f2bf(g * wv);
            }
        }
}

// GEMM2: accW = G @ W2stacked  ([8192x2560] @ [2560x1024])
__global__ __launch_bounds__(256) void gemm2(const ushort_t* __restrict__ G,
                                             const ushort_t* __restrict__ w2t,
                                             float* __restrict__ accW) {
    __shared__ __align__(16) ushort_t As[128 * 64];
    __shared__ __align__(16) ushort_t Bs[128 * 64];
    int n0 = blockIdx.x * 128;
    int m0 = blockIdx.y * 128;
    f32x4 acc[4][4];
    gemm_core_128x128(G + (size_t)m0 * KG2, KG2,
                      w2t + (size_t)n0 * KG2, KG2,
                      KG2, As, Bs, acc);
    int tid = threadIdx.x, lane = tid & 63, w = tid >> 6;
    int wr = w >> 1, wc = w & 1, lrow = lane & 15, quad = lane >> 4;
    #pragma unroll
    for (int mt = 0; mt < 4; mt++)
        #pragma unroll
        for (int r = 0; r < 4; r++) {
            int row = m0 + wr * 64 + mt * 16 + quad * 4 + r;
            #pragma unroll
            for (int nt = 0; nt < 4; nt++) {
                int col = n0 + wc * 64 + nt * 16 + lrow;
                accW[(size_t)row * C_DIM + col] = acc[mt][nt][r];
            }
        }
}

// out[b][c][p] = accW[t][c] + feat[b][c][p]
__global__ __launch_bounds__(256) void finalk(const float* __restrict__ accW,
                                              const float* __restrict__ feat,
                                              float* __restrict__ out) {
    int p0 = blockIdx.x * 64, c0 = blockIdx.y * 64, b = blockIdx.z;
    __shared__ float lds[64][65];
    int tid = threadIdx.x, lo = tid & 63, hi = tid >> 6;
    #pragma unroll
    for (int i = 0; i < 16; i++) {
        int p_l = i * 4 + hi;
        lds[p_l][lo] = accW[((size_t)(b * HW_N + p0 + p_l)) * C_DIM + c0 + lo];
    }
    __syncthreads();
    #pragma unroll
    for (int i = 0; i < 16; i++) {
        int c_l = i * 4 + hi;
        size_t o = ((size_t)b * C_DIM + c0 + c_l) * HW_N + p0 + lo;
        out[o] = lds[lo][c_l] + feat[o];
    }
}

// ---------------- launch ----------------
extern "C" void kernel_launch(void* const* d_in, const int* in_sizes, int n_in,
                              void* d_out, int out_size, void* d_ws, size_t ws_size,
                              hipStream_t stream) {
    (void)in_sizes; (void)n_in; (void)out_size; (void)ws_size;
    const float* feat = (const float*)d_in[0];
    const float* ar   = (const float*)d_in[1];
    const float* ln_s = (const float*)d_in[2];
    const float* ln_b = (const float*)d_in[3];
    const float* w1   = (const float*)d_in[4];
    const float* w2   = (const float*)d_in[5];
    float* out = (float*)d_out;
    char* ws = (char*)d_ws;

    ushort_t* w1t   = (ushort_t*)(ws + 0);          // 5,242,880
    ushort_t* w2t   = (ushort_t*)(ws + 5242880);    // 5,242,880
    float*    bias1 = (float*)(ws + 10485760);      // 10,240
    float*    meanp = (float*)(ws + 10496000);      // 32,768
    float*    rstdp = (float*)(ws + 10528768);      // 32,768
    ushort_t* normG = (ushort_t*)(ws + 10561536);   // 16,777,216
    float*    wsel  = (float*)(ws + 27338752);      // 327,680
    ushort_t* G     = (ushort_t*)(ws + 27666432);   // 41,943,040
    float*    accW  = (float*)(ws + 69609472);      // 33,554,432

    dim3 blk(256);
    prep_w1t<<<dim3(4, 16, A_N), blk, 0, stream>>>(w1, ln_s, w1t);
    prep_w2t<<<dim3(40, 16), blk, 0, stream>>>(w2, w2t);
    hipMemsetAsync(bias1, 0, A_N * CR * sizeof(float), stream);
    bias1k<<<dim3(16, A_N), blk, 0, stream>>>(w1, ln_b, bias1);
    ln_stats<<<dim3(128), blk, 0, stream>>>(feat, meanp, rstdp);
    normk<<<dim3(64, 16, B_N), blk, 0, stream>>>(feat, meanp, rstdp, normG);
    wselk<<<dim3(32), blk, 0, stream>>>(ar, wsel);
    gemm1<<<dim3(2, 64, A_N), blk, 0, stream>>>(normG, w1t, bias1, wsel, G);
    gemm2<<<dim3(8, 64), blk, 0, stream>>>(G, w2t, accW);
    finalk<<<dim3(64, 16, B_N), blk, 0, stream>>>(accW, feat, out);
}

// Round 2
// 297.523 us; speedup vs baseline: 1.2376x; 1.2376x over previous
//
#include <hip/hip_runtime.h>
#include <hip/hip_bf16.h>
#include <math.h>

#define C_DIM 1024
#define CR    256
#define A_N   10
#define NANCH 3
#define B_N   2
#define HW_N  4096
#define NTOK  (B_N*HW_N)   // 8192
#define KG2   (A_N*CR)     // 2560

typedef unsigned short ushort_t;
typedef __attribute__((ext_vector_type(4))) float f32x4;
typedef __attribute__((ext_vector_type(8))) short bf16x8;

__device__ __forceinline__ ushort_t f2bf(float x) {
    __hip_bfloat16 h = __float2bfloat16(x);
    return *reinterpret_cast<ushort_t*>(&h);
}

// ---------------- weight prep ----------------
// w1t[a][d][c] = bf16(ln_scale[a][c] * w1[a][c][d])   (N-major for NT gemm)
__global__ __launch_bounds__(256) void prep_w1t(const float* __restrict__ w1,
                                                const float* __restrict__ ln_s,
                                                ushort_t* __restrict__ w1t) {
    int d0 = blockIdx.x * 64, c0 = blockIdx.y * 64, a = blockIdx.z;
    __shared__ float lds[64][65];
    int tid = threadIdx.x, lo = tid & 63, hi = tid >> 6;
    #pragma unroll
    for (int i = 0; i < 16; i++) {
        int c_l = i * 4 + hi;
        lds[c_l][lo] = w1[((size_t)a * C_DIM + c0 + c_l) * CR + d0 + lo] * ln_s[a * C_DIM + c0 + c_l];
    }
    __syncthreads();
    #pragma unroll
    for (int i = 0; i < 16; i++) {
        int d_l = i * 4 + hi;
        w1t[((size_t)a * CR + d0 + d_l) * C_DIM + c0 + lo] = f2bf(lds[lo][d_l]);
    }
}

// w2t[c][a*CR+d] = bf16(w2[a][d][c])  i.e. transpose of flat [2560][1024]
__global__ __launch_bounds__(256) void prep_w2t(const float* __restrict__ w2,
                                                ushort_t* __restrict__ w2t) {
    int k0 = blockIdx.x * 64, c0 = blockIdx.y * 64;
    __shared__ float lds[64][65];
    int tid = threadIdx.x, lo = tid & 63, hi = tid >> 6;
    #pragma unroll
    for (int i = 0; i < 16; i++) {
        int k_l = i * 4 + hi;
        lds[k_l][lo] = w2[((size_t)k0 + k_l) * C_DIM + c0 + lo];
    }
    __syncthreads();
    #pragma unroll
    for (int i = 0; i < 16; i++) {
        int c_l = i * 4 + hi;
        w2t[((size_t)c0 + c_l) * KG2 + k0 + lo] = f2bf(lds[lo][c_l]);
    }
}

// bias1[a][d] = sum_c ln_bias[a][c] * w1[a][c][d]
__global__ __launch_bounds__(256) void bias1k(const float* __restrict__ w1,
                                              const float* __restrict__ ln_b,
                                              float* __restrict__ bias1) {
    int c0 = blockIdx.x * 64, a = blockIdx.y, d = threadIdx.x;
    float s = 0.f;
    for (int c = c0; c < c0 + 64; c++)
        s += ln_b[a * C_DIM + c] * w1[((size_t)a * C_DIM + c) * CR + d];
    atomicAdd(&bias1[a * CR + d], s);
}

// ---------------- LN (partial sums, high parallelism) ----------------
// grid (64, 8, 2): block = 64 pixels x 128 channels; atomicAdd partials.
__global__ __launch_bounds__(256) void ln_part(const float* __restrict__ feat,
                                               float* __restrict__ sumv,
                                               float* __restrict__ sumq) {
    int p0 = blockIdx.x * 64, c0 = blockIdx.y * 128, b = blockIdx.z;
    int tid = threadIdx.x, p = tid & 63, cs = tid >> 6;
    float s = 0.f, s2 = 0.f;
    #pragma unroll
    for (int c = cs; c < 128; c += 4) {
        float v = feat[((size_t)b * C_DIM + c0 + c) * HW_N + p0 + p];
        s += v; s2 += v * v;
    }
    __shared__ float sh[8][64];
    sh[cs][p] = s; sh[cs + 4][p] = s2;
    __syncthreads();
    if (tid < 64) {
        float ss = sh[0][tid] + sh[1][tid] + sh[2][tid] + sh[3][tid];
        float qq = sh[4][tid] + sh[5][tid] + sh[6][tid] + sh[7][tid];
        int t = b * HW_N + p0 + tid;
        atomicAdd(&sumv[t], ss);
        atomicAdd(&sumq[t], qq);
    }
}

// normG[t][c] = bf16((feat - mean)*rstd), token-major; finalizes LN stats inline
__global__ __launch_bounds__(256) void normk(const float* __restrict__ feat,
                                             const float* __restrict__ sumv,
                                             const float* __restrict__ sumq,
                                             ushort_t* __restrict__ normG) {
    int p0 = blockIdx.x * 64, c0 = blockIdx.y * 64, b = blockIdx.z;
    __shared__ float lds[64][65];
    int tid = threadIdx.x, lo = tid & 63, hi = tid >> 6;
    #pragma unroll
    for (int i = 0; i < 16; i++) {
        int c_l = i * 4 + hi;
        lds[c_l][lo] = feat[((size_t)b * C_DIM + c0 + c_l) * HW_N + p0 + lo];
    }
    __syncthreads();
    #pragma unroll
    for (int i = 0; i < 16; i++) {
        int p_l = i * 4 + hi;
        int t = b * HW_N + p0 + p_l;
        float m = sumv[t] * (1.f / C_DIM);
        float q = sumq[t] * (1.f / C_DIM);
        float r = rsqrtf(q - m * m + 1e-5f);
        normG[(size_t)t * C_DIM + c0 + lo] = f2bf((lds[lo][p_l] - m) * r);
    }
}

// ---------------- selection weights ----------------
__global__ __launch_bounds__(256) void wselk(const float* __restrict__ ar,
                                             float* __restrict__ wsel) {
    int t = blockIdx.x * 256 + threadIdx.x;  // < 8192
    int b = t >> 12, p = t & (HW_N - 1);
    const float THR[9] = {1.0f/9.0f, 1.0f/7.0f, 0.2f, 1.0f/3.0f, 1.0f, 3.0f, 5.0f, 7.0f, 9.0f};
    int cnt[A_N];
    #pragma unroll
    for (int a = 0; a < A_N; a++) cnt[a] = 0;
    #pragma unroll
    for (int na = 0; na < NANCH; na++) {
        float v = ar[(size_t)b * NANCH * HW_N + na * HW_N + p];
        int idx = 0;
        #pragma unroll
        for (int i = 0; i < 9; i++) idx += (v > THR[i]) ? 1 : 0;
        #pragma unroll
        for (int a = 0; a < A_N; a++) cnt[a] += (idx == a) ? 1 : 0;
    }
    #pragma unroll
    for (int a = 0; a < A_N; a++) wsel[a * NTOK + t] = cnt[a] * (1.0f / 3.0f);
}

// ---------------- 128x128 bf16 MFMA GEMM core (NT: A[M][K], B[N][K]) ----------------
// XOR-swizzled LDS: lane l stages source 16B-chunk (l&7)^(l>>3&7) of row l>>3,
// so LDS slot j of row r holds chunk j^(r&7). Fragment reads then spread each
// quad's 16 lanes across all 8 bank-groups (2 lanes/group = conflict-free).
__device__ __forceinline__ void gemm_core_128x128(
    const ushort_t* __restrict__ Ag, int lda,
    const ushort_t* __restrict__ Bg, int ldb,
    int K, ushort_t* As, ushort_t* Bs, f32x4 acc[4][4]) {
    const int tid = threadIdx.x;
    const int lane = tid & 63;
    const int w = tid >> 6;
    const int wr = w >> 1, wc = w & 1;
    const int lrow = lane & 15;
    const int quad = lane >> 4;

    #pragma unroll
    for (int i = 0; i < 4; i++)
        #pragma unroll
        for (int j = 0; j < 4; j++)
            #pragma unroll
            for (int e = 0; e < 4; e++) acc[i][j][e] = 0.f;

    const int lrow8 = lane >> 3;                  // 0..7 row within staging group
    const int schunk = (lane & 7) ^ lrow8;        // swizzled source chunk
    const int srow = w * 32 + lrow8;              // staging row (+i*8)
    const int scol = schunk * 8;                  // source col (8 bf16 = 16B)
    const int swzr = lrow & 7;                    // read-side swizzle key

    for (int k0 = 0; k0 < K; k0 += 64) {
        __syncthreads();
        #pragma unroll
        for (int i = 0; i < 4; i++) {
            const ushort_t* gA = Ag + (size_t)(srow + i * 8) * lda + k0 + scol;
            __builtin_amdgcn_global_load_lds(
                (__attribute__((address_space(1))) void*)gA,
                (__attribute__((address_space(3))) void*)(As + (w * 32 + i * 8) * 64),
                16, 0, 0);
            const ushort_t* gB = Bg + (size_t)(srow + i * 8) * ldb + k0 + scol;
            __builtin_amdgcn_global_load_lds(
                (__attribute__((address_space(1))) void*)gB,
                (__attribute__((address_space(3))) void*)(Bs + (w * 32 + i * 8) * 64),
                16, 0, 0);
        }
        __syncthreads();
        #pragma unroll
        for (int ks = 0; ks < 2; ks++) {
            const int cidx = ((ks * 4 + quad) ^ swzr) * 8;  // swizzled slot
            bf16x8 af[4], bfr[4];
            #pragma unroll
            for (int mt = 0; mt < 4; mt++)
                af[mt] = *(const bf16x8*)(As + (wr * 64 + mt * 16 + lrow) * 64 + cidx);
            #pragma unroll
            for (int nt = 0; nt < 4; nt++)
                bfr[nt] = *(const bf16x8*)(Bs + (wc * 64 + nt * 16 + lrow) * 64 + cidx);
            #pragma unroll
            for (int mt = 0; mt < 4; mt++)
                #pragma unroll
                for (int nt = 0; nt < 4; nt++)
                    acc[mt][nt] = __builtin_amdgcn_mfma_f32_16x16x32_bf16(af[mt], bfr[nt], acc[mt][nt], 0, 0, 0);
        }
    }
}

// GEMM1: H = gelu(norm @ w1'[a] + bias1[a]) * wsel[a]  -> G[t][a*256+d] bf16
__global__ __launch_bounds__(256) void gemm1(const ushort_t* __restrict__ normG,
                                             const ushort_t* __restrict__ w1t,
                                             const float* __restrict__ bias1,
                                             const float* __restrict__ wsel,
                                             ushort_t* __restrict__ G) {
    __shared__ __align__(16) ushort_t As[128 * 64];
    __shared__ __align__(16) ushort_t Bs[128 * 64];
    int n0 = blockIdx.x * 128;
    int m0 = blockIdx.y * 128;
    int a = blockIdx.z;
    f32x4 acc[4][4];
    gemm_core_128x128(normG + (size_t)m0 * C_DIM, C_DIM,
                      w1t + ((size_t)a * CR + n0) * C_DIM, C_DIM,
                      C_DIM, As, Bs, acc);
    int tid = threadIdx.x, lane = tid & 63, w = tid >> 6;
    int wr = w >> 1, wc = w & 1, lrow = lane & 15, quad = lane >> 4;
    #pragma unroll
    for (int mt = 0; mt < 4; mt++)
        #pragma unroll
        for (int r = 0; r < 4; r++) {
            int row = m0 + wr * 64 + mt * 16 + quad * 4 + r;
            float wv = wsel[a * NTOK + row];
            #pragma unroll
            for (int nt = 0; nt < 4; nt++) {
                int col = n0 + wc * 64 + nt * 16 + lrow;
                float v = acc[mt][nt][r] + bias1[a * CR + col];
                float g = 0.5f * v * (1.0f + erff(v * 0.70710678118654752f));
                G[(size_t)row * KG2 + a * CR + col] = f2bf(g * wv);
            }
        }
}

// GEMM2: accW = G @ W2stacked  ([8192x2560] @ [2560x1024])
__global__ __launch_bounds__(256) void gemm2(const ushort_t* __restrict__ G,
                                             const ushort_t* __restrict__ w2t,
                                             float* __restrict__ accW) {
    __shared__ __align__(16) ushort_t As[128 * 64];
    __shared__ __align__(16) ushort_t Bs[128 * 64];
    int n0 = blockIdx.x * 128;
    int m0 = blockIdx.y * 128;
    f32x4 acc[4][4];
    gemm_core_128x128(G + (size_t)m0 * KG2, KG2,
                      w2t + (size_t)n0 * KG2, KG2,
                      KG2, As, Bs, acc);
    int tid = threadIdx.x, lane = tid & 63, w = tid >> 6;
    int wr = w >> 1, wc = w & 1, lrow = lane & 15, quad = lane >> 4;
    #pragma unroll
    for (int mt = 0; mt < 4; mt++)
        #pragma unroll
        for (int r = 0; r < 4; r++) {
            int row = m0 + wr * 64 + mt * 16 + quad * 4 + r;
            #pragma unroll
            for (int nt = 0; nt < 4; nt++) {
                int col = n0 + wc * 64 + nt * 16 + lrow;
                accW[(size_t)row * C_DIM + col] = acc[mt][nt][r];
            }
        }
}

// out[b][c][p] = accW[t][c] + feat[b][c][p]
__global__ __launch_bounds__(256) void finalk(const float* __restrict__ accW,
                                              const float* __restrict__ feat,
                                              float* __restrict__ out) {
    int p0 = blockIdx.x * 64, c0 = blockIdx.y * 64, b = blockIdx.z;
    __shared__ float lds[64][65];
    int tid = threadIdx.x, lo = tid & 63, hi = tid >> 6;
    #pragma unroll
    for (int i = 0; i < 16; i++) {
        int p_l = i * 4 + hi;
        lds[p_l][lo] = accW[((size_t)(b * HW_N + p0 + p_l)) * C_DIM + c0 + lo];
    }
    __syncthreads();
    #pragma unroll
    for (int i = 0; i < 16; i++) {
        int c_l = i * 4 + hi;
        size_t o = ((size_t)b * C_DIM + c0 + c_l) * HW_N + p0 + lo;
        out[o] = lds[lo][c_l] + feat[o];
    }
}

// ---------------- launch ----------------
extern "C" void kernel_launch(void* const* d_in, const int* in_sizes, int n_in,
                              void* d_out, int out_size, void* d_ws, size_t ws_size,
                              hipStream_t stream) {
    (void)in_sizes; (void)n_in; (void)out_size; (void)ws_size;
    const float* feat = (const float*)d_in[0];
    const float* ar   = (const float*)d_in[1];
    const float* ln_s = (const float*)d_in[2];
    const float* ln_b = (const float*)d_in[3];
    const float* w1   = (const float*)d_in[4];
    const float* w2   = (const float*)d_in[5];
    float* out = (float*)d_out;
    char* ws = (char*)d_ws;

    ushort_t* w1t   = (ushort_t*)(ws + 0);          // 5,242,880
    ushort_t* w2t   = (ushort_t*)(ws + 5242880);    // 5,242,880
    float*    bias1 = (float*)(ws + 10485760);      // 10,240
    float*    sumv  = (float*)(ws + 10496000);      // 32,768
    float*    sumq  = (float*)(ws + 10528768);      // 32,768
    ushort_t* normG = (ushort_t*)(ws + 10561536);   // 16,777,216
    float*    wsel  = (float*)(ws + 27338752);      // 327,680
    ushort_t* G     = (ushort_t*)(ws + 27666432);   // 41,943,040
    float*    accW  = (float*)(ws + 69609472);      // 33,554,432

    dim3 blk(256);
    prep_w1t<<<dim3(4, 16, A_N), blk, 0, stream>>>(w1, ln_s, w1t);
    prep_w2t<<<dim3(40, 16), blk, 0, stream>>>(w2, w2t);
    hipMemsetAsync(bias1, 0, A_N * CR * sizeof(float), stream);
    hipMemsetAsync(sumv, 0, NTOK * sizeof(float), stream);
    hipMemsetAsync(sumq, 0, NTOK * sizeof(float), stream);
    bias1k<<<dim3(16, A_N), blk, 0, stream>>>(w1, ln_b, bias1);
    ln_part<<<dim3(64, 8, B_N), blk, 0, stream>>>(feat, sumv, sumq);
    normk<<<dim3(64, 16, B_N), blk, 0, stream>>>(feat, sumv, sumq, normG);
    wselk<<<dim3(32), blk, 0, stream>>>(ar, wsel);
    gemm1<<<dim3(2, 64, A_N), blk, 0, stream>>>(normG, w1t, bias1, wsel, G);
    gemm2<<<dim3(8, 64), blk, 0, stream>>>(G, w2t, accW);
    finalk<<<dim3(64, 16, B_N), blk, 0, stream>>>(accW, feat, out);
}

// Round 3
// 264.156 us; speedup vs baseline: 1.3939x; 1.1263x over previous
//
#include <hip/hip_runtime.h>
#include <hip/hip_bf16.h>
#include <math.h>

#define C_DIM 1024
#define CR    256
#define A_N   10
#define NANCH 3
#define B_N   2
#define HW_N  4096
#define NTOK  (B_N*HW_N)   // 8192
#define KG2   (A_N*CR)     // 2560

typedef unsigned short ushort_t;
typedef __attribute__((ext_vector_type(4))) float f32x4;
typedef __attribute__((ext_vector_type(8))) short bf16x8;

__device__ __forceinline__ ushort_t f2bf(float x) {
    __hip_bfloat16 h = __float2bfloat16(x);
    return *reinterpret_cast<ushort_t*>(&h);
}

// tanh-form GELU via sigmoid identity: 0.5x(1+tanh(u)) = x*sigmoid(2u).
// |err| vs exact erf-GELU < ~1e-3 absolute — below bf16 rounding of G.
__device__ __forceinline__ float fast_gelu(float x) {
    float t = x * x;
    float u = x * (-1.5957691216f - 0.0713548163f * t);  // -2*0.79788456*(x+0.044715x^3)
    float e = __expf(u);
    return x * __frcp_rn(1.0f + e);
}

// ---------------- weight prep ----------------
// w1t[a][d][c] = bf16(ln_scale[a][c] * w1[a][c][d])   (N-major for NT gemm)
__global__ __launch_bounds__(256) void prep_w1t(const float* __restrict__ w1,
                                                const float* __restrict__ ln_s,
                                                ushort_t* __restrict__ w1t) {
    int d0 = blockIdx.x * 64, c0 = blockIdx.y * 64, a = blockIdx.z;
    __shared__ float lds[64][65];
    int tid = threadIdx.x, lo = tid & 63, hi = tid >> 6;
    #pragma unroll
    for (int i = 0; i < 16; i++) {
        int c_l = i * 4 + hi;
        lds[c_l][lo] = w1[((size_t)a * C_DIM + c0 + c_l) * CR + d0 + lo] * ln_s[a * C_DIM + c0 + c_l];
    }
    __syncthreads();
    #pragma unroll
    for (int i = 0; i < 16; i++) {
        int d_l = i * 4 + hi;
        w1t[((size_t)a * CR + d0 + d_l) * C_DIM + c0 + lo] = f2bf(lds[lo][d_l]);
    }
}

// w2t[c][a*CR+d] = bf16(w2[a][d][c])  i.e. transpose of flat [2560][1024]
__global__ __launch_bounds__(256) void prep_w2t(const float* __restrict__ w2,
                                                ushort_t* __restrict__ w2t) {
    int k0 = blockIdx.x * 64, c0 = blockIdx.y * 64;
    __shared__ float lds[64][65];
    int tid = threadIdx.x, lo = tid & 63, hi = tid >> 6;
    #pragma unroll
    for (int i = 0; i < 16; i++) {
        int k_l = i * 4 + hi;
        lds[k_l][lo] = w2[((size_t)k0 + k_l) * C_DIM + c0 + lo];
    }
    __syncthreads();
    #pragma unroll
    for (int i = 0; i < 16; i++) {
        int c_l = i * 4 + hi;
        w2t[((size_t)c0 + c_l) * KG2 + k0 + lo] = f2bf(lds[lo][c_l]);
    }
}

// bias1[a][d] = sum_c ln_bias[a][c] * w1[a][c][d]
__global__ __launch_bounds__(256) void bias1k(const float* __restrict__ w1,
                                              const float* __restrict__ ln_b,
                                              float* __restrict__ bias1) {
    int c0 = blockIdx.x * 64, a = blockIdx.y, d = threadIdx.x;
    float s = 0.f;
    for (int c = c0; c < c0 + 64; c++)
        s += ln_b[a * C_DIM + c] * w1[((size_t)a * C_DIM + c) * CR + d];
    atomicAdd(&bias1[a * CR + d], s);
}

// ---------------- LN (partial sums, high parallelism) ----------------
__global__ __launch_bounds__(256) void ln_part(const float* __restrict__ feat,
                                               float* __restrict__ sumv,
                                               float* __restrict__ sumq) {
    int p0 = blockIdx.x * 64, c0 = blockIdx.y * 128, b = blockIdx.z;
    int tid = threadIdx.x, p = tid & 63, cs = tid >> 6;
    float s = 0.f, s2 = 0.f;
    #pragma unroll
    for (int c = cs; c < 128; c += 4) {
        float v = feat[((size_t)b * C_DIM + c0 + c) * HW_N + p0 + p];
        s += v; s2 += v * v;
    }
    __shared__ float sh[8][64];
    sh[cs][p] = s; sh[cs + 4][p] = s2;
    __syncthreads();
    if (tid < 64) {
        float ss = sh[0][tid] + sh[1][tid] + sh[2][tid] + sh[3][tid];
        float qq = sh[4][tid] + sh[5][tid] + sh[6][tid] + sh[7][tid];
        int t = b * HW_N + p0 + tid;
        atomicAdd(&sumv[t], ss);
        atomicAdd(&sumq[t], qq);
    }
}

// normG[t][c] = bf16((feat - mean)*rstd), token-major; finalizes LN stats inline
__global__ __launch_bounds__(256) void normk(const float* __restrict__ feat,
                                             const float* __restrict__ sumv,
                                             const float* __restrict__ sumq,
                                             ushort_t* __restrict__ normG) {
    int p0 = blockIdx.x * 64, c0 = blockIdx.y * 64, b = blockIdx.z;
    __shared__ float lds[64][65];
    int tid = threadIdx.x, lo = tid & 63, hi = tid >> 6;
    #pragma unroll
    for (int i = 0; i < 16; i++) {
        int c_l = i * 4 + hi;
        lds[c_l][lo] = feat[((size_t)b * C_DIM + c0 + c_l) * HW_N + p0 + lo];
    }
    __syncthreads();
    #pragma unroll
    for (int i = 0; i < 16; i++) {
        int p_l = i * 4 + hi;
        int t = b * HW_N + p0 + p_l;
        float m = sumv[t] * (1.f / C_DIM);
        float q = sumq[t] * (1.f / C_DIM);
        float r = rsqrtf(q - m * m + 1e-5f);
        normG[(size_t)t * C_DIM + c0 + lo] = f2bf((lds[lo][p_l] - m) * r);
    }
}

// ---------------- selection weights ----------------
__global__ __launch_bounds__(256) void wselk(const float* __restrict__ ar,
                                             float* __restrict__ wsel) {
    int t = blockIdx.x * 256 + threadIdx.x;  // < 8192
    int b = t >> 12, p = t & (HW_N - 1);
    const float THR[9] = {1.0f/9.0f, 1.0f/7.0f, 0.2f, 1.0f/3.0f, 1.0f, 3.0f, 5.0f, 7.0f, 9.0f};
    int cnt[A_N];
    #pragma unroll
    for (int a = 0; a < A_N; a++) cnt[a] = 0;
    #pragma unroll
    for (int na = 0; na < NANCH; na++) {
        float v = ar[(size_t)b * NANCH * HW_N + na * HW_N + p];
        int idx = 0;
        #pragma unroll
        for (int i = 0; i < 9; i++) idx += (v > THR[i]) ? 1 : 0;
        #pragma unroll
        for (int a = 0; a < A_N; a++) cnt[a] += (idx == a) ? 1 : 0;
    }
    #pragma unroll
    for (int a = 0; a < A_N; a++) wsel[a * NTOK + t] = cnt[a] * (1.0f / 3.0f);
}

// ---------------- 128x128 bf16 MFMA GEMM core (NT: A[M][K], B[N][K]) ----------------
// XOR-swizzled LDS (round-2 win: bank conflicts 1.57e7 -> 0).
__device__ __forceinline__ void gemm_core_128x128(
    const ushort_t* __restrict__ Ag, int lda,
    const ushort_t* __restrict__ Bg, int ldb,
    int K, ushort_t* As, ushort_t* Bs, f32x4 acc[4][4]) {
    const int tid = threadIdx.x;
    const int lane = tid & 63;
    const int w = tid >> 6;
    const int wr = w >> 1, wc = w & 1;
    const int lrow = lane & 15;
    const int quad = lane >> 4;

    #pragma unroll
    for (int i = 0; i < 4; i++)
        #pragma unroll
        for (int j = 0; j < 4; j++)
            #pragma unroll
            for (int e = 0; e < 4; e++) acc[i][j][e] = 0.f;

    const int lrow8 = lane >> 3;
    const int schunk = (lane & 7) ^ lrow8;
    const int srow = w * 32 + lrow8;
    const int scol = schunk * 8;
    const int swzr = lrow & 7;

    for (int k0 = 0; k0 < K; k0 += 64) {
        __syncthreads();
        #pragma unroll
        for (int i = 0; i < 4; i++) {
            const ushort_t* gA = Ag + (size_t)(srow + i * 8) * lda + k0 + scol;
            __builtin_amdgcn_global_load_lds(
                (__attribute__((address_space(1))) void*)gA,
                (__attribute__((address_space(3))) void*)(As + (w * 32 + i * 8) * 64),
                16, 0, 0);
            const ushort_t* gB = Bg + (size_t)(srow + i * 8) * ldb + k0 + scol;
            __builtin_amdgcn_global_load_lds(
                (__attribute__((address_space(1))) void*)gB,
                (__attribute__((address_space(3))) void*)(Bs + (w * 32 + i * 8) * 64),
                16, 0, 0);
        }
        __syncthreads();
        #pragma unroll
        for (int ks = 0; ks < 2; ks++) {
            const int cidx = ((ks * 4 + quad) ^ swzr) * 8;
            bf16x8 af[4], bfr[4];
            #pragma unroll
            for (int mt = 0; mt < 4; mt++)
                af[mt] = *(const bf16x8*)(As + (wr * 64 + mt * 16 + lrow) * 64 + cidx);
            #pragma unroll
            for (int nt = 0; nt < 4; nt++)
                bfr[nt] = *(const bf16x8*)(Bs + (wc * 64 + nt * 16 + lrow) * 64 + cidx);
            #pragma unroll
            for (int mt = 0; mt < 4; mt++)
                #pragma unroll
                for (int nt = 0; nt < 4; nt++)
                    acc[mt][nt] = __builtin_amdgcn_mfma_f32_16x16x32_bf16(af[mt], bfr[nt], acc[mt][nt], 0, 0, 0);
        }
    }
}

// GEMM1: H = gelu(norm @ w1'[a] + bias1[a]) * wsel[a]  -> G[t][a*256+d] bf16
__global__ __launch_bounds__(256) void gemm1(const ushort_t* __restrict__ normG,
                                             const ushort_t* __restrict__ w1t,
                                             const float* __restrict__ bias1,
                                             const float* __restrict__ wsel,
                                             ushort_t* __restrict__ G) {
    __shared__ __align__(16) ushort_t As[128 * 64];
    __shared__ __align__(16) ushort_t Bs[128 * 64];
    int n0 = blockIdx.x * 128;
    int m0 = blockIdx.y * 128;
    int a = blockIdx.z;
    f32x4 acc[4][4];
    gemm_core_128x128(normG + (size_t)m0 * C_DIM, C_DIM,
                      w1t + ((size_t)a * CR + n0) * C_DIM, C_DIM,
                      C_DIM, As, Bs, acc);
    int tid = threadIdx.x, lane = tid & 63, w = tid >> 6;
    int wr = w >> 1, wc = w & 1, lrow = lane & 15, quad = lane >> 4;
    float bi[4];
    #pragma unroll
    for (int nt = 0; nt < 4; nt++)
        bi[nt] = bias1[a * CR + n0 + wc * 64 + nt * 16 + lrow];
    #pragma unroll
    for (int mt = 0; mt < 4; mt++)
        #pragma unroll
        for (int r = 0; r < 4; r++) {
            int row = m0 + wr * 64 + mt * 16 + quad * 4 + r;
            float wv = wsel[a * NTOK + row];
            #pragma unroll
            for (int nt = 0; nt < 4; nt++) {
                int col = n0 + wc * 64 + nt * 16 + lrow;
                float v = acc[mt][nt][r] + bi[nt];
                G[(size_t)row * KG2 + a * CR + col] = f2bf(fast_gelu(v) * wv);
            }
        }
}

// GEMM2: out[b][c][p] = (G @ W2stacked)[t][c] + feat[b][c][p]
// Fused transpose+add epilogue through LDS (accW round-trip eliminated).
__global__ __launch_bounds__(256) void gemm2(const ushort_t* __restrict__ G,
                                             const ushort_t* __restrict__ w2t,
                                             const float* __restrict__ feat,
                                             float* __restrict__ out) {
    __shared__ __align__(16) char smem[32768];
    ushort_t* As = (ushort_t*)smem;
    ushort_t* Bs = (ushort_t*)(smem + 16384);
    float* tbuf = (float*)smem;          // 32 cols x 129 floats = 16512 B
    int n0 = blockIdx.x * 128;
    int m0 = blockIdx.y * 128;
    f32x4 acc[4][4];
    gemm_core_128x128(G + (size_t)m0 * KG2, KG2,
                      w2t + (size_t)n0 * KG2, KG2,
                      KG2, As, Bs, acc);
    int tid = threadIdx.x, lane = tid & 63, w = tid >> 6;
    int wr = w >> 1, wc = w & 1, lrow = lane & 15, quad = lane >> 4;
    int b = m0 >> 12;                    // 128-row tiles never cross batch (4096 % 128 == 0)
    int p_base = m0 & (HW_N - 1);
    #pragma unroll
    for (int cp = 0; cp < 4; cp++) {     // 32 output channels per pass
        __syncthreads();
        int nh = cp - 2 * wc;            // which nt-pair this wave contributes
        if (nh == 0 || nh == 1) {
            #pragma unroll
            for (int nt2 = 0; nt2 < 2; nt2++) {
                int nt = nh * 2 + nt2;
                int cl = nt2 * 16 + lrow;            // col within the 32-pass
                #pragma unroll
                for (int mt = 0; mt < 4; mt++)
                    #pragma unroll
                    for (int r = 0; r < 4; r++) {
                        int rowl = wr * 64 + mt * 16 + quad * 4 + r;
                        tbuf[cl * 129 + rowl] = acc[mt][nt][r];
                    }
            }
        }
        __syncthreads();
        #pragma unroll
        for (int j = 0; j < 8; j++) {
            int c_idx = w * 8 + j;
            int c = n0 + cp * 32 + c_idx;
            #pragma unroll
            for (int h = 0; h < 2; h++) {
                int rowl = h * 64 + lane;
                size_t o = ((size_t)b * C_DIM + c) * HW_N + p_base + rowl;
                out[o] = tbuf[c_idx * 129 + rowl] + feat[o];
            }
        }
    }
}

// ---------------- launch ----------------
extern "C" void kernel_launch(void* const* d_in, const int* in_sizes, int n_in,
                              void* d_out, int out_size, void* d_ws, size_t ws_size,
                              hipStream_t stream) {
    (void)in_sizes; (void)n_in; (void)out_size; (void)ws_size;
    const float* feat = (const float*)d_in[0];
    const float* ar   = (const float*)d_in[1];
    const float* ln_s = (const float*)d_in[2];
    const float* ln_b = (const float*)d_in[3];
    const float* w1   = (const float*)d_in[4];
    const float* w2   = (const float*)d_in[5];
    float* out = (float*)d_out;
    char* ws = (char*)d_ws;

    ushort_t* w1t   = (ushort_t*)(ws + 0);          // 5,242,880
    ushort_t* w2t   = (ushort_t*)(ws + 5242880);    // 5,242,880
    float*    bias1 = (float*)(ws + 10485760);      // 10,240
    float*    sumv  = (float*)(ws + 10496000);      // 32,768
    float*    sumq  = (float*)(ws + 10528768);      // 32,768
    ushort_t* normG = (ushort_t*)(ws + 10561536);   // 16,777,216
    float*    wsel  = (float*)(ws + 27338752);      // 327,680
    ushort_t* G     = (ushort_t*)(ws + 27666432);   // 41,943,040

    dim3 blk(256);
    prep_w1t<<<dim3(4, 16, A_N), blk, 0, stream>>>(w1, ln_s, w1t);
    prep_w2t<<<dim3(40, 16), blk, 0, stream>>>(w2, w2t);
    hipMemsetAsync(bias1, 0, A_N * CR * sizeof(float), stream);
    hipMemsetAsync(sumv, 0, NTOK * sizeof(float), stream);
    hipMemsetAsync(sumq, 0, NTOK * sizeof(float), stream);
    bias1k<<<dim3(16, A_N), blk, 0, stream>>>(w1, ln_b, bias1);
    ln_part<<<dim3(64, 8, B_N), blk, 0, stream>>>(feat, sumv, sumq);
    normk<<<dim3(64, 16, B_N), blk, 0, stream>>>(feat, sumv, sumq, normG);
    wselk<<<dim3(32), blk, 0, stream>>>(ar, wsel);
    gemm1<<<dim3(2, 64, A_N), blk, 0, stream>>>(normG, w1t, bias1, wsel, G);
    gemm2<<<dim3(8, 64), blk, 0, stream>>>(G, w2t, feat, out);
}